// Round 10
// baseline (282.571 us; speedup 1.0000x reference)
//
#include <hip/hip_runtime.h>
#include <hip/hip_bf16.h>
#include <cstdint>
#include <cstddef>

// MultiHeadAttention: B=4, T=2048, D=1024, H=16, dh=64, fp32 in/out.
// R10: ONE mechanism -- GEMM occupancy 2 -> 3 blocks/CU via
// __launch_bounds__(256,3) (VGPR cap 170, no spill expected; LDS 3x32KB
// fits). m114: this structure's throughput comes from implicit wave-level
// overlap across resident blocks; analysis was at ~3 blocks/CU, we ran 2.
// attn byte-identical to R9 (verified 107us; XCD remap kept: FETCH
// 141->26MB). GEMM inner loops / epilogues / cvt unchanged from R9.

#define SEQ 2048
#define DM 1024

typedef __attribute__((ext_vector_type(8))) short bf16x8;
typedef __attribute__((ext_vector_type(4))) short bf16x4;
typedef __attribute__((ext_vector_type(4))) float f32x4;

static __device__ __forceinline__ short f2bf(float f) {
  union { float f; uint32_t u; } v; v.f = f;
  uint32_t r = v.u + 0x7fffu + ((v.u >> 16) & 1u);
  return (short)(r >> 16);
}

typedef const __attribute__((address_space(1))) unsigned int* gas_ptr;
typedef __attribute__((address_space(3))) unsigned int* las_ptr;
static __device__ __forceinline__ void gl2lds16(const void* g, void* l) {
  __builtin_amdgcn_global_load_lds((gas_ptr)g, (las_ptr)l, 16, 0, 0);
}

// truncating pack of two fp32 into bf16 pair: one v_perm_b32
static __device__ __forceinline__ unsigned permhi(float a_odd, float a_even) {
  union { float f; unsigned u; } x, y; x.f = a_odd; y.f = a_even;
  return __builtin_amdgcn_perm(x.u, y.u, 0x07060302u);
}
static __device__ __forceinline__ bf16x8 pack8t(const float* e) {
  union { bf16x8 v; unsigned u[4]; } r;
  r.u[0] = permhi(e[1], e[0]);
  r.u[1] = permhi(e[3], e[2]);
  r.u[2] = permhi(e[5], e[4]);
  r.u[3] = permhi(e[7], e[6]);
  return r.v;
}

// swizzle: chunk c (16B) of tile row r stored at LDS chunk r*8 + (c ^ swz(r))
static __device__ __forceinline__ int swz(int r) {
  return (r & 3) | (((r >> 3) & 1) << 2);
}

// ---------------- Kernel 0: fp32 -> bf16 convert ----------------
__global__ __launch_bounds__(256)
void cvt_bf16(const float* __restrict__ src, short* __restrict__ dst) {
  int i = blockIdx.x * 256 + threadIdx.x;
  float4 v = ((const float4*)src)[i];
  bf16x4 p = { f2bf(v.x), f2bf(v.y), f2bf(v.z), f2bf(v.w) };
  ((bf16x4*)dst)[i] = p;
}

// merged convert: blocks [0,n1) do src1->dst1, rest do src2->dst2
__global__ __launch_bounds__(256)
void cvt_bf16_2(const float* __restrict__ src1, short* __restrict__ dst1, int n1,
                const float* __restrict__ src2, short* __restrict__ dst2) {
  int b = blockIdx.x;
  if (b < n1) {
    int i = b * 256 + threadIdx.x;
    float4 v = ((const float4*)src1)[i];
    bf16x4 p = { f2bf(v.x), f2bf(v.y), f2bf(v.z), f2bf(v.w) };
    ((bf16x4*)dst1)[i] = p;
  } else {
    int i = (b - n1) * 256 + threadIdx.x;
    float4 v = ((const float4*)src2)[i];
    bf16x4 p = { f2bf(v.x), f2bf(v.y), f2bf(v.z), f2bf(v.w) };
    ((bf16x4*)dst2)[i] = p;
  }
}

// ---------------- Kernel 1: QKV projection GEMM (prefetch + counted vmcnt, 3 blk/CU) ----------------
__global__ __launch_bounds__(256, 3)
void qkv_gemm(const short* __restrict__ Xb, const short* __restrict__ Wb,
              const float* __restrict__ bias,
              short* __restrict__ Q, short* __restrict__ K,
              short* __restrict__ Vt) {
  __shared__ short As[2][128 * 64];
  __shared__ short Bs[2][128 * 64];
  const int tid  = threadIdx.x;
  const int m0   = blockIdx.x * 128;
  const int n0   = blockIdx.y * 128;
  const int lane = tid & 63;
  const int w    = tid >> 6;
  const int wm   = (w >> 1) * 64, wn = (w & 1) * 64;
  const int l15  = lane & 15, quad = lane >> 4;

  // staging map (swizzled source, linear LDS dest)
  int g_row[4], g_col[4];
#pragma unroll
  for (int p = 0; p < 4; p++) {
    int r = p * 32 + w * 8 + (lane >> 3);
    g_row[p] = r;
    g_col[p] = ((lane & 7) ^ swz(r)) << 3;
  }
  // cached swizzled read byte-offsets
  int aoff[4][2], boff[4][2];
#pragma unroll
  for (int i = 0; i < 4; i++)
#pragma unroll
    for (int ks = 0; ks < 2; ks++) {
      int Ra = wm + i * 16 + l15;
      aoff[i][ks] = Ra * 128 + (((ks * 4 + quad) ^ swz(Ra)) << 4);
      int Rb = wn + i * 16 + l15;
      boff[i][ks] = Rb * 128 + (((ks * 4 + quad) ^ swz(Rb)) << 4);
    }

  f32x4 acc[4][4];
  for (int i = 0; i < 4; i++)
    for (int j = 0; j < 4; j++) acc[i][j] = (f32x4)0.0f;

  // prologue: stage K-tile 0 into buffer 0
#pragma unroll
  for (int p = 0; p < 4; p++) {
    gl2lds16(&Xb[(size_t)(m0 + g_row[p]) * DM + g_col[p]], &As[0][(p * 32 + w * 8) * 64]);
    gl2lds16(&Wb[(size_t)(n0 + g_row[p]) * DM + g_col[p]], &Bs[0][(p * 32 + w * 8) * 64]);
  }

  for (int t = 0; t < 16; t++) {
    const int cur = t & 1;
    if (t + 1 < 16) {
      const int kk = (t + 1) * 64;
#pragma unroll
      for (int p = 0; p < 4; p++) {
        gl2lds16(&Xb[(size_t)(m0 + g_row[p]) * DM + kk + g_col[p]], &As[cur ^ 1][(p * 32 + w * 8) * 64]);
        gl2lds16(&Wb[(size_t)(n0 + g_row[p]) * DM + kk + g_col[p]], &Bs[cur ^ 1][(p * 32 + w * 8) * 64]);
      }
      asm volatile("s_waitcnt vmcnt(8)" ::: "memory");   // tile t landed; t+1 in flight
    } else {
      asm volatile("s_waitcnt vmcnt(0)" ::: "memory");
    }
    __builtin_amdgcn_s_barrier();
    __builtin_amdgcn_sched_barrier(0);

    const char* Ab = (const char*)&As[cur][0];
    const char* Bb = (const char*)&Bs[cur][0];
#pragma unroll
    for (int ks = 0; ks < 2; ks++) {
      bf16x8 af[4], bfr[4];
      for (int i = 0; i < 4; i++) af[i]  = *(const bf16x8*)(Ab + aoff[i][ks]);
      for (int j = 0; j < 4; j++) bfr[j] = *(const bf16x8*)(Bb + boff[j][ks]);
      for (int i = 0; i < 4; i++)
        for (int j = 0; j < 4; j++)
          acc[i][j] = __builtin_amdgcn_mfma_f32_16x16x32_bf16(af[i], bfr[j], acc[i][j], 0, 0, 0);
    }
    __builtin_amdgcn_sched_barrier(0);
    __builtin_amdgcn_s_barrier();     // readers of buf done before next stage overwrites
    __builtin_amdgcn_sched_barrier(0);
  }

  const float C1 = 0.18033688011112042f;   // 0.125 * log2(e), folded into Q
  const int qkv = n0 >> 10;
  for (int i = 0; i < 4; i++) {
    const int m = m0 + wm + i * 16 + quad * 4;
    const int bb = m >> 11, t = m & 2047;
    for (int j = 0; j < 4; j++) {
      const int f  = n0 + wn + j * 16 + l15;
      const int fi = f & 1023;
      const int h  = fi >> 6, d = fi & 63;
      const float bv = bias[f];
      if (qkv == 2) {
        bf16x4 pk = { f2bf(acc[i][j][0] + bv), f2bf(acc[i][j][1] + bv),
                      f2bf(acc[i][j][2] + bv), f2bf(acc[i][j][3] + bv) };
        *(bf16x4*)&Vt[((size_t)(bb * 16 + h) * 64 + d) * SEQ + t] = pk;
      } else {
        short* dst = (qkv == 0) ? Q : K;
        const float sc = (qkv == 0) ? C1 : 1.0f;
        size_t base = ((size_t)(bb * 16 + h) * SEQ + t) * 64 + d;
        for (int r = 0; r < 4; r++)
          dst[base + (size_t)r * 64] = f2bf((acc[i][j][r] + bv) * sc);
      }
    }
  }
}

// ---------------- Kernel 2: flash attention (LDS-staged K/V) ----------------
// Byte-identical to R9 (verified 107us; XCD-aware remap keeps per-XCD K/V
// L2-resident: FETCH 26MB). Schedule untouched (R4/R8 lesson).
__global__ __launch_bounds__(256, 4)
void attn(const short* __restrict__ Q, const short* __restrict__ K,
          const short* __restrict__ Vt, short* __restrict__ ctx) {
  __shared__ short Ks[2][64 * 64];   // 8 KB per buffer, swizzled chunks
  __shared__ short Vs[2][64 * 64];
  const int tid  = threadIdx.x;
  const int w    = tid >> 6, lane = tid & 63;
  const int l15  = lane & 15, quad = lane >> 4;

  // XCD-aware remap (T1): linear id L, xcd = L&7 (HW round-robin),
  // bh = ((L>>3)>>4)*8 + xcd, bx = (L>>3)&15. Bijective on [0,1024).
  const int L    = blockIdx.y * 16 + blockIdx.x;
  const int m_   = L >> 3;
  const int bh   = ((m_ >> 4) << 3) | (L & 7);
  const int qr   = (m_ & 15) * 128 + w * 32;

  const short* Kb = &K[(size_t)bh * SEQ * 64];
  const short* Vb = &Vt[(size_t)bh * 64 * SEQ];

  const int kperm = (l15 >> 2) * 8 + (l15 & 3);   // + tau*4 -> permuted K row

  int dr[2], dc[2];
#pragma unroll
  for (int p = 0; p < 2; p++) {
    int ci = p * 256 + w * 64 + lane;
    dr[p] = ci >> 3;
    dc[p] = (ci & 7) ^ swz(ci >> 3);
  }
  const short* kp[2];
  const short* vp[2];
#pragma unroll
  for (int p = 0; p < 2; p++) {
    kp[p] = &Kb[(size_t)(64 + dr[p]) * 64 + dc[p] * 8];
    vp[p] = &Vb[(size_t)dr[p] * SEQ + 64 + dc[p] * 8];
  }

  int koff[2][2][2][2];   // [buf][blk][tau][ks]
  int voff[2][4][2];      // [buf][dt][blk]
#pragma unroll
  for (int blk = 0; blk < 2; blk++)
#pragma unroll
    for (int tau = 0; tau < 2; tau++)
#pragma unroll
      for (int ks = 0; ks < 2; ks++) {
        int R = blk * 32 + kperm + tau * 4;
        int c = (ks * 4 + quad) ^ swz(R);
        int off = (R * 8 + c) * 16;
        koff[0][blk][tau][ks] = off;
        koff[1][blk][tau][ks] = off + 8192;
      }
#pragma unroll
  for (int dt = 0; dt < 4; dt++)
#pragma unroll
    for (int blk = 0; blk < 2; blk++) {
      int R = dt * 16 + l15;
      int c = (blk * 4 + quad) ^ swz(R);
      int off = (R * 8 + c) * 16;
      voff[0][dt][blk] = off;
      voff[1][dt][blk] = off + 8192;
    }
  const char* KsB = (const char*)&Ks[0][0];
  const char* VsB = (const char*)&Vs[0][0];

  bf16x8 qf[2][2];
#pragma unroll
  for (int mt = 0; mt < 2; mt++)
#pragma unroll
    for (int ks = 0; ks < 2; ks++)
      qf[mt][ks] = *(const bf16x8*)&Q[(size_t)bh * SEQ * 64 + (size_t)(qr + mt * 16 + l15) * 64 + ks * 32 + quad * 8];

  f32x4 O[2][4];
#pragma unroll
  for (int mt = 0; mt < 2; mt++)
    for (int dt = 0; dt < 4; dt++) O[mt][dt] = (f32x4)0.0f;
  f32x4 psA[2];
  psA[0] = (f32x4)0.0f; psA[1] = (f32x4)0.0f;
  const short one_bf = (short)0x3F80;
  const bf16x8 ones = { one_bf, one_bf, one_bf, one_bf, one_bf, one_bf, one_bf, one_bf };

  // prologue: DMA tile 0 into buffer 0
#pragma unroll
  for (int p = 0; p < 2; p++) {
    gl2lds16(&Kb[(size_t)dr[p] * 64 + dc[p] * 8],  &Ks[0][(p * 256 + w * 64) * 8]);
    gl2lds16(&Vb[(size_t)dr[p] * SEQ + dc[p] * 8], &Vs[0][(p * 256 + w * 64) * 8]);
  }
  __syncthreads();

  for (int k0 = 0; k0 < SEQ; k0 += 128) {
#pragma unroll
    for (int half = 0; half < 2; half++) {
      // prefetch next tile into the other buffer
      const bool doPf = (half == 0) || (k0 + 128 < SEQ);
      if (doPf) {
#pragma unroll
        for (int p = 0; p < 2; p++) {
          gl2lds16(kp[p], &Ks[half ^ 1][(p * 256 + w * 64) * 8]);
          gl2lds16(vp[p], &Vs[half ^ 1][(p * 256 + w * 64) * 8]);
        }
      }
#pragma unroll
      for (int p = 0; p < 2; p++) { kp[p] += 64 * 64; vp[p] += 64; }

      // K fragments (cached offsets)
      bf16x8 kf[2][2][2];
#pragma unroll
      for (int blk = 0; blk < 2; blk++)
#pragma unroll
        for (int tau = 0; tau < 2; tau++)
#pragma unroll
          for (int ks = 0; ks < 2; ks++)
            kf[blk][tau][ks] = *(const bf16x8*)(KsB + koff[half][blk][tau][ks]);

      // S^T = K Q^T
      f32x4 S[2][2][2];
#pragma unroll
      for (int mt = 0; mt < 2; mt++)
#pragma unroll
        for (int blk = 0; blk < 2; blk++) {
          f32x4 S0 = (f32x4)0.0f, S1 = (f32x4)0.0f;
#pragma unroll
          for (int ks = 0; ks < 2; ks++) {
            S0 = __builtin_amdgcn_mfma_f32_16x16x32_bf16(kf[blk][0][ks], qf[mt][ks], S0, 0, 0, 0);
            S1 = __builtin_amdgcn_mfma_f32_16x16x32_bf16(kf[blk][1][ks], qf[mt][ks], S1, 0, 0, 0);
          }
          S[mt][blk][0] = S0; S[mt][blk][1] = S1;
        }

      // V^T fragments (cached offsets)
      bf16x8 vf[4][2];
#pragma unroll
      for (int dt = 0; dt < 4; dt++)
#pragma unroll
        for (int blk = 0; blk < 2; blk++)
          vf[dt][blk] = *(const bf16x8*)(VsB + voff[half][dt][blk]);

      // p = 2^S ; truncating v_perm pack into PV B-frags
      bf16x8 pp[2][2];
#pragma unroll
      for (int mt = 0; mt < 2; mt++)
#pragma unroll
        for (int blk = 0; blk < 2; blk++) {
          float e[8];
#pragma unroll
          for (int r = 0; r < 4; r++) {
            e[r]     = exp2f(S[mt][blk][0][r]);
            e[4 + r] = exp2f(S[mt][blk][1][r]);
          }
          pp[mt][blk] = pack8t(e);
        }

      // O^T += V^T P^T ; psum += ones·P^T
#pragma unroll
      for (int blk = 0; blk < 2; blk++) {
#pragma unroll
        for (int dt = 0; dt < 4; dt++) {
          O[0][dt] = __builtin_amdgcn_mfma_f32_16x16x32_bf16(vf[dt][blk], pp[0][blk], O[0][dt], 0, 0, 0);
          O[1][dt] = __builtin_amdgcn_mfma_f32_16x16x32_bf16(vf[dt][blk], pp[1][blk], O[1][dt], 0, 0, 0);
        }
        psA[0] = __builtin_amdgcn_mfma_f32_16x16x32_bf16(ones, pp[0][blk], psA[0], 0, 0, 0);
        psA[1] = __builtin_amdgcn_mfma_f32_16x16x32_bf16(ones, pp[1][blk], psA[1], 0, 0, 0);
      }

      __syncthreads();
    }
  }

  const int bb = bh >> 4, h = bh & 15;
#pragma unroll
  for (int mt = 0; mt < 2; mt++) {
    float rinv = 1.0f / psA[mt][0];
    const int t = qr + mt * 16 + l15;
#pragma unroll
    for (int dt = 0; dt < 4; dt++) {
      bf16x4 ov = { f2bf(O[mt][dt][0] * rinv), f2bf(O[mt][dt][1] * rinv),
                    f2bf(O[mt][dt][2] * rinv), f2bf(O[mt][dt][3] * rinv) };
      *(bf16x4*)&ctx[(size_t)(bb * SEQ + t) * DM + h * 64 + dt * 16 + quad * 4] = ov;
    }
  }
}

// ---------------- Kernel 3: output projection GEMM (counted vmcnt, 3 blk/CU) ----------------
__global__ __launch_bounds__(256, 3)
void out_gemm(const short* __restrict__ Cx, const short* __restrict__ Ob,
              const float* __restrict__ bias, float* __restrict__ Y) {
  __shared__ short As[2][128 * 64];
  __shared__ short Bs[2][128 * 64];
  const int tid  = threadIdx.x;
  const int m0   = blockIdx.x * 128;
  const int n0   = blockIdx.y * 128;
  const int lane = tid & 63;
  const int w    = tid >> 6;
  const int wm   = (w >> 1) * 64, wn = (w & 1) * 64;
  const int l15  = lane & 15, quad = lane >> 4;

  int g_row[4], g_col[4];
#pragma unroll
  for (int p = 0; p < 4; p++) {
    int r = p * 32 + w * 8 + (lane >> 3);
    g_row[p] = r;
    g_col[p] = ((lane & 7) ^ swz(r)) << 3;
  }
  int aoff[4][2], boff[4][2];
#pragma unroll
  for (int i = 0; i < 4; i++)
#pragma unroll
    for (int ks = 0; ks < 2; ks++) {
      int Ra = wm + i * 16 + l15;
      aoff[i][ks] = Ra * 128 + (((ks * 4 + quad) ^ swz(Ra)) << 4);
      int Rb = wn + i * 16 + l15;
      boff[i][ks] = Rb * 128 + (((ks * 4 + quad) ^ swz(Rb)) << 4);
    }

  f32x4 acc[4][4];
  for (int i = 0; i < 4; i++)
    for (int j = 0; j < 4; j++) acc[i][j] = (f32x4)0.0f;

#pragma unroll
  for (int p = 0; p < 4; p++) {
    gl2lds16(&Cx[(size_t)(m0 + g_row[p]) * DM + g_col[p]], &As[0][(p * 32 + w * 8) * 64]);
    gl2lds16(&Ob[(size_t)(n0 + g_row[p]) * DM + g_col[p]], &Bs[0][(p * 32 + w * 8) * 64]);
  }

  for (int t = 0; t < 16; t++) {
    const int cur = t & 1;
    if (t + 1 < 16) {
      const int kk = (t + 1) * 64;
#pragma unroll
      for (int p = 0; p < 4; p++) {
        gl2lds16(&Cx[(size_t)(m0 + g_row[p]) * DM + kk + g_col[p]], &As[cur ^ 1][(p * 32 + w * 8) * 64]);
        gl2lds16(&Ob[(size_t)(n0 + g_row[p]) * DM + kk + g_col[p]], &Bs[cur ^ 1][(p * 32 + w * 8) * 64]);
      }
      asm volatile("s_waitcnt vmcnt(8)" ::: "memory");
    } else {
      asm volatile("s_waitcnt vmcnt(0)" ::: "memory");
    }
    __builtin_amdgcn_s_barrier();
    __builtin_amdgcn_sched_barrier(0);

    const char* Ab = (const char*)&As[cur][0];
    const char* Bb = (const char*)&Bs[cur][0];
#pragma unroll
    for (int ks = 0; ks < 2; ks++) {
      bf16x8 af[4], bfr[4];
      for (int i = 0; i < 4; i++) af[i]  = *(const bf16x8*)(Ab + aoff[i][ks]);
      for (int j = 0; j < 4; j++) bfr[j] = *(const bf16x8*)(Bb + boff[j][ks]);
      for (int i = 0; i < 4; i++)
        for (int j = 0; j < 4; j++)
          acc[i][j] = __builtin_amdgcn_mfma_f32_16x16x32_bf16(af[i], bfr[j], acc[i][j], 0, 0, 0);
    }
    __builtin_amdgcn_sched_barrier(0);
    __builtin_amdgcn_s_barrier();
    __builtin_amdgcn_sched_barrier(0);
  }

  for (int i = 0; i < 4; i++) {
    const int m = m0 + wm + i * 16 + quad * 4;
    for (int j = 0; j < 4; j++) {
      const int n = n0 + wn + j * 16 + l15;
      const float bv = bias[n];
      for (int r = 0; r < 4; r++)
        Y[(size_t)(m + r) * DM + n] = acc[i][j][r] + bv;
    }
  }
}

extern "C" void kernel_launch(void* const* d_in, const int* in_sizes, int n_in,
                              void* d_out, int out_size, void* d_ws, size_t ws_size,
                              hipStream_t stream) {
  const float* x     = (const float*)d_in[0];
  const float* qkv_w = (const float*)d_in[1];
  const float* qkv_b = (const float*)d_in[2];
  const float* out_w = (const float*)d_in[3];
  const float* out_b = (const float*)d_in[4];
  float* out = (float*)d_out;

  const size_t NBH = (size_t)4 * 16 * SEQ * 64;   // 8,388,608 elements
  short* Q   = (short*)d_ws;
  short* K   = Q + NBH;
  short* Vt  = K + NBH;      // after attn, reused as Ob (bf16 out_w)
  short* ctx = Vt + NBH;     // before attn, holds Xb (bf16 x)
  short* Xb  = ctx;
  short* Ob  = Vt;
  short* Wb  = (short*)d_out; // bf16 qkv_w scratch in d_out (dead until out_gemm)

  cvt_bf16_2<<<dim3(8192 + 3072), 256, 0, stream>>>(x, Xb, 8192, qkv_w, Wb);
  qkv_gemm<<<dim3(64, 24), 256, 0, stream>>>(Xb, Wb, qkv_b, Q, K, Vt);
  attn<<<dim3(SEQ / 128, 64), 256, 0, stream>>>(Q, K, Vt, ctx);
  cvt_bf16<<<dim3(1024), 256, 0, stream>>>(out_w, Ob);
  out_gemm<<<dim3(64, 8), 256, 0, stream>>>(ctx, Ob, out_b, out);
}

// Round 11
// 276.988 us; speedup vs baseline: 1.0202x; 1.0202x over previous
//
#include <hip/hip_runtime.h>
#include <hip/hip_bf16.h>
#include <cstdint>
#include <cstddef>

// MultiHeadAttention: B=4, T=2048, D=1024, H=16, dh=64, fp32 in/out.
// R11: config = measured-best (R6 GEMMs w/ counted vmcnt @ 2 blk/CU
// [R10's occ-3 reverted: +3us] + R9 attn w/ XCD remap [FETCH 141->26MB]).
// ONE new mechanism, host-side + guarded: if ws_size has 2MiB slack past
// the 64MiB in use, Ob (bf16 out_w) moves to ws+64MiB instead of aliasing
// Vt -- removes the attn->cvt ordering constraint, so ALL three fp32->bf16
// converts merge into the single front kernel (5 launches -> 4). Fallback
// path (small ws) is byte-identical to R9's sequencing.

#define SEQ 2048
#define DM 1024

typedef __attribute__((ext_vector_type(8))) short bf16x8;
typedef __attribute__((ext_vector_type(4))) short bf16x4;
typedef __attribute__((ext_vector_type(4))) float f32x4;

static __device__ __forceinline__ short f2bf(float f) {
  union { float f; uint32_t u; } v; v.f = f;
  uint32_t r = v.u + 0x7fffu + ((v.u >> 16) & 1u);
  return (short)(r >> 16);
}

typedef const __attribute__((address_space(1))) unsigned int* gas_ptr;
typedef __attribute__((address_space(3))) unsigned int* las_ptr;
static __device__ __forceinline__ void gl2lds16(const void* g, void* l) {
  __builtin_amdgcn_global_load_lds((gas_ptr)g, (las_ptr)l, 16, 0, 0);
}

// truncating pack of two fp32 into bf16 pair: one v_perm_b32
static __device__ __forceinline__ unsigned permhi(float a_odd, float a_even) {
  union { float f; unsigned u; } x, y; x.f = a_odd; y.f = a_even;
  return __builtin_amdgcn_perm(x.u, y.u, 0x07060302u);
}
static __device__ __forceinline__ bf16x8 pack8t(const float* e) {
  union { bf16x8 v; unsigned u[4]; } r;
  r.u[0] = permhi(e[1], e[0]);
  r.u[1] = permhi(e[3], e[2]);
  r.u[2] = permhi(e[5], e[4]);
  r.u[3] = permhi(e[7], e[6]);
  return r.v;
}

// swizzle: chunk c (16B) of tile row r stored at LDS chunk r*8 + (c ^ swz(r))
static __device__ __forceinline__ int swz(int r) {
  return (r & 3) | (((r >> 3) & 1) << 2);
}

// ---------------- Kernel 0: fp32 -> bf16 convert ----------------
__global__ __launch_bounds__(256)
void cvt_bf16(const float* __restrict__ src, short* __restrict__ dst) {
  int i = blockIdx.x * 256 + threadIdx.x;
  float4 v = ((const float4*)src)[i];
  bf16x4 p = { f2bf(v.x), f2bf(v.y), f2bf(v.z), f2bf(v.w) };
  ((bf16x4*)dst)[i] = p;
}

// merged convert, two segments
__global__ __launch_bounds__(256)
void cvt_bf16_2(const float* __restrict__ src1, short* __restrict__ dst1, int n1,
                const float* __restrict__ src2, short* __restrict__ dst2) {
  int b = blockIdx.x;
  const float* s; short* d; int i;
  if (b < n1) { s = src1; d = dst1; i = b * 256 + threadIdx.x; }
  else        { s = src2; d = dst2; i = (b - n1) * 256 + threadIdx.x; }
  float4 v = ((const float4*)s)[i];
  bf16x4 p = { f2bf(v.x), f2bf(v.y), f2bf(v.z), f2bf(v.w) };
  ((bf16x4*)d)[i] = p;
}

// merged convert, three segments
__global__ __launch_bounds__(256)
void cvt_bf16_3(const float* __restrict__ src1, short* __restrict__ dst1, int n1,
                const float* __restrict__ src2, short* __restrict__ dst2, int n2,
                const float* __restrict__ src3, short* __restrict__ dst3) {
  int b = blockIdx.x;
  const float* s; short* d; int i;
  if (b < n1)           { s = src1; d = dst1; i = b * 256 + threadIdx.x; }
  else if (b < n1 + n2) { s = src2; d = dst2; i = (b - n1) * 256 + threadIdx.x; }
  else                  { s = src3; d = dst3; i = (b - n1 - n2) * 256 + threadIdx.x; }
  float4 v = ((const float4*)s)[i];
  bf16x4 p = { f2bf(v.x), f2bf(v.y), f2bf(v.z), f2bf(v.w) };
  ((bf16x4*)d)[i] = p;
}

// ---------------- Kernel 1: QKV projection GEMM (prefetch + counted vmcnt) ----------------
__global__ __launch_bounds__(256, 2)
void qkv_gemm(const short* __restrict__ Xb, const short* __restrict__ Wb,
              const float* __restrict__ bias,
              short* __restrict__ Q, short* __restrict__ K,
              short* __restrict__ Vt) {
  __shared__ short As[2][128 * 64];
  __shared__ short Bs[2][128 * 64];
  const int tid  = threadIdx.x;
  const int m0   = blockIdx.x * 128;
  const int n0   = blockIdx.y * 128;
  const int lane = tid & 63;
  const int w    = tid >> 6;
  const int wm   = (w >> 1) * 64, wn = (w & 1) * 64;
  const int l15  = lane & 15, quad = lane >> 4;

  // staging map (swizzled source, linear LDS dest)
  int g_row[4], g_col[4];
#pragma unroll
  for (int p = 0; p < 4; p++) {
    int r = p * 32 + w * 8 + (lane >> 3);
    g_row[p] = r;
    g_col[p] = ((lane & 7) ^ swz(r)) << 3;
  }
  // cached swizzled read byte-offsets
  int aoff[4][2], boff[4][2];
#pragma unroll
  for (int i = 0; i < 4; i++)
#pragma unroll
    for (int ks = 0; ks < 2; ks++) {
      int Ra = wm + i * 16 + l15;
      aoff[i][ks] = Ra * 128 + (((ks * 4 + quad) ^ swz(Ra)) << 4);
      int Rb = wn + i * 16 + l15;
      boff[i][ks] = Rb * 128 + (((ks * 4 + quad) ^ swz(Rb)) << 4);
    }

  f32x4 acc[4][4];
  for (int i = 0; i < 4; i++)
    for (int j = 0; j < 4; j++) acc[i][j] = (f32x4)0.0f;

  // prologue: stage K-tile 0 into buffer 0
#pragma unroll
  for (int p = 0; p < 4; p++) {
    gl2lds16(&Xb[(size_t)(m0 + g_row[p]) * DM + g_col[p]], &As[0][(p * 32 + w * 8) * 64]);
    gl2lds16(&Wb[(size_t)(n0 + g_row[p]) * DM + g_col[p]], &Bs[0][(p * 32 + w * 8) * 64]);
  }

  for (int t = 0; t < 16; t++) {
    const int cur = t & 1;
    if (t + 1 < 16) {
      const int kk = (t + 1) * 64;
#pragma unroll
      for (int p = 0; p < 4; p++) {
        gl2lds16(&Xb[(size_t)(m0 + g_row[p]) * DM + kk + g_col[p]], &As[cur ^ 1][(p * 32 + w * 8) * 64]);
        gl2lds16(&Wb[(size_t)(n0 + g_row[p]) * DM + kk + g_col[p]], &Bs[cur ^ 1][(p * 32 + w * 8) * 64]);
      }
      asm volatile("s_waitcnt vmcnt(8)" ::: "memory");   // tile t landed; t+1 in flight
    } else {
      asm volatile("s_waitcnt vmcnt(0)" ::: "memory");
    }
    __builtin_amdgcn_s_barrier();
    __builtin_amdgcn_sched_barrier(0);

    const char* Ab = (const char*)&As[cur][0];
    const char* Bb = (const char*)&Bs[cur][0];
#pragma unroll
    for (int ks = 0; ks < 2; ks++) {
      bf16x8 af[4], bfr[4];
      for (int i = 0; i < 4; i++) af[i]  = *(const bf16x8*)(Ab + aoff[i][ks]);
      for (int j = 0; j < 4; j++) bfr[j] = *(const bf16x8*)(Bb + boff[j][ks]);
      for (int i = 0; i < 4; i++)
        for (int j = 0; j < 4; j++)
          acc[i][j] = __builtin_amdgcn_mfma_f32_16x16x32_bf16(af[i], bfr[j], acc[i][j], 0, 0, 0);
    }
    __builtin_amdgcn_sched_barrier(0);
    __builtin_amdgcn_s_barrier();     // readers of buf done before next stage overwrites
    __builtin_amdgcn_sched_barrier(0);
  }

  const float C1 = 0.18033688011112042f;   // 0.125 * log2(e), folded into Q
  const int qkv = n0 >> 10;
  for (int i = 0; i < 4; i++) {
    const int m = m0 + wm + i * 16 + quad * 4;
    const int bb = m >> 11, t = m & 2047;
    for (int j = 0; j < 4; j++) {
      const int f  = n0 + wn + j * 16 + l15;
      const int fi = f & 1023;
      const int h  = fi >> 6, d = fi & 63;
      const float bv = bias[f];
      if (qkv == 2) {
        bf16x4 pk = { f2bf(acc[i][j][0] + bv), f2bf(acc[i][j][1] + bv),
                      f2bf(acc[i][j][2] + bv), f2bf(acc[i][j][3] + bv) };
        *(bf16x4*)&Vt[((size_t)(bb * 16 + h) * 64 + d) * SEQ + t] = pk;
      } else {
        short* dst = (qkv == 0) ? Q : K;
        const float sc = (qkv == 0) ? C1 : 1.0f;
        size_t base = ((size_t)(bb * 16 + h) * SEQ + t) * 64 + d;
        for (int r = 0; r < 4; r++)
          dst[base + (size_t)r * 64] = f2bf((acc[i][j][r] + bv) * sc);
      }
    }
  }
}

// ---------------- Kernel 2: flash attention (LDS-staged K/V) ----------------
// Byte-identical to R9 (verified 107us; XCD-aware remap keeps per-XCD K/V
// L2-resident: FETCH 26MB). Schedule untouched (R4/R8 lesson).
__global__ __launch_bounds__(256, 4)
void attn(const short* __restrict__ Q, const short* __restrict__ K,
          const short* __restrict__ Vt, short* __restrict__ ctx) {
  __shared__ short Ks[2][64 * 64];   // 8 KB per buffer, swizzled chunks
  __shared__ short Vs[2][64 * 64];
  const int tid  = threadIdx.x;
  const int w    = tid >> 6, lane = tid & 63;
  const int l15  = lane & 15, quad = lane >> 4;

  // XCD-aware remap (T1): linear id L, xcd = L&7 (HW round-robin),
  // bh = ((L>>3)>>4)*8 + xcd, bx = (L>>3)&15. Bijective on [0,1024).
  const int L    = blockIdx.y * 16 + blockIdx.x;
  const int m_   = L >> 3;
  const int bh   = ((m_ >> 4) << 3) | (L & 7);
  const int qr   = (m_ & 15) * 128 + w * 32;

  const short* Kb = &K[(size_t)bh * SEQ * 64];
  const short* Vb = &Vt[(size_t)bh * 64 * SEQ];

  const int kperm = (l15 >> 2) * 8 + (l15 & 3);   // + tau*4 -> permuted K row

  int dr[2], dc[2];
#pragma unroll
  for (int p = 0; p < 2; p++) {
    int ci = p * 256 + w * 64 + lane;
    dr[p] = ci >> 3;
    dc[p] = (ci & 7) ^ swz(ci >> 3);
  }
  const short* kp[2];
  const short* vp[2];
#pragma unroll
  for (int p = 0; p < 2; p++) {
    kp[p] = &Kb[(size_t)(64 + dr[p]) * 64 + dc[p] * 8];
    vp[p] = &Vb[(size_t)dr[p] * SEQ + 64 + dc[p] * 8];
  }

  int koff[2][2][2][2];   // [buf][blk][tau][ks]
  int voff[2][4][2];      // [buf][dt][blk]
#pragma unroll
  for (int blk = 0; blk < 2; blk++)
#pragma unroll
    for (int tau = 0; tau < 2; tau++)
#pragma unroll
      for (int ks = 0; ks < 2; ks++) {
        int R = blk * 32 + kperm + tau * 4;
        int c = (ks * 4 + quad) ^ swz(R);
        int off = (R * 8 + c) * 16;
        koff[0][blk][tau][ks] = off;
        koff[1][blk][tau][ks] = off + 8192;
      }
#pragma unroll
  for (int dt = 0; dt < 4; dt++)
#pragma unroll
    for (int blk = 0; blk < 2; blk++) {
      int R = dt * 16 + l15;
      int c = (blk * 4 + quad) ^ swz(R);
      int off = (R * 8 + c) * 16;
      voff[0][dt][blk] = off;
      voff[1][dt][blk] = off + 8192;
    }
  const char* KsB = (const char*)&Ks[0][0];
  const char* VsB = (const char*)&Vs[0][0];

  bf16x8 qf[2][2];
#pragma unroll
  for (int mt = 0; mt < 2; mt++)
#pragma unroll
    for (int ks = 0; ks < 2; ks++)
      qf[mt][ks] = *(const bf16x8*)&Q[(size_t)bh * SEQ * 64 + (size_t)(qr + mt * 16 + l15) * 64 + ks * 32 + quad * 8];

  f32x4 O[2][4];
#pragma unroll
  for (int mt = 0; mt < 2; mt++)
    for (int dt = 0; dt < 4; dt++) O[mt][dt] = (f32x4)0.0f;
  f32x4 psA[2];
  psA[0] = (f32x4)0.0f; psA[1] = (f32x4)0.0f;
  const short one_bf = (short)0x3F80;
  const bf16x8 ones = { one_bf, one_bf, one_bf, one_bf, one_bf, one_bf, one_bf, one_bf };

  // prologue: DMA tile 0 into buffer 0
#pragma unroll
  for (int p = 0; p < 2; p++) {
    gl2lds16(&Kb[(size_t)dr[p] * 64 + dc[p] * 8],  &Ks[0][(p * 256 + w * 64) * 8]);
    gl2lds16(&Vb[(size_t)dr[p] * SEQ + dc[p] * 8], &Vs[0][(p * 256 + w * 64) * 8]);
  }
  __syncthreads();

  for (int k0 = 0; k0 < SEQ; k0 += 128) {
#pragma unroll
    for (int half = 0; half < 2; half++) {
      // prefetch next tile into the other buffer
      const bool doPf = (half == 0) || (k0 + 128 < SEQ);
      if (doPf) {
#pragma unroll
        for (int p = 0; p < 2; p++) {
          gl2lds16(kp[p], &Ks[half ^ 1][(p * 256 + w * 64) * 8]);
          gl2lds16(vp[p], &Vs[half ^ 1][(p * 256 + w * 64) * 8]);
        }
      }
#pragma unroll
      for (int p = 0; p < 2; p++) { kp[p] += 64 * 64; vp[p] += 64; }

      // K fragments (cached offsets)
      bf16x8 kf[2][2][2];
#pragma unroll
      for (int blk = 0; blk < 2; blk++)
#pragma unroll
        for (int tau = 0; tau < 2; tau++)
#pragma unroll
          for (int ks = 0; ks < 2; ks++)
            kf[blk][tau][ks] = *(const bf16x8*)(KsB + koff[half][blk][tau][ks]);

      // S^T = K Q^T
      f32x4 S[2][2][2];
#pragma unroll
      for (int mt = 0; mt < 2; mt++)
#pragma unroll
        for (int blk = 0; blk < 2; blk++) {
          f32x4 S0 = (f32x4)0.0f, S1 = (f32x4)0.0f;
#pragma unroll
          for (int ks = 0; ks < 2; ks++) {
            S0 = __builtin_amdgcn_mfma_f32_16x16x32_bf16(kf[blk][0][ks], qf[mt][ks], S0, 0, 0, 0);
            S1 = __builtin_amdgcn_mfma_f32_16x16x32_bf16(kf[blk][1][ks], qf[mt][ks], S1, 0, 0, 0);
          }
          S[mt][blk][0] = S0; S[mt][blk][1] = S1;
        }

      // V^T fragments (cached offsets)
      bf16x8 vf[4][2];
#pragma unroll
      for (int dt = 0; dt < 4; dt++)
#pragma unroll
        for (int blk = 0; blk < 2; blk++)
          vf[dt][blk] = *(const bf16x8*)(VsB + voff[half][dt][blk]);

      // p = 2^S ; truncating v_perm pack into PV B-frags
      bf16x8 pp[2][2];
#pragma unroll
      for (int mt = 0; mt < 2; mt++)
#pragma unroll
        for (int blk = 0; blk < 2; blk++) {
          float e[8];
#pragma unroll
          for (int r = 0; r < 4; r++) {
            e[r]     = exp2f(S[mt][blk][0][r]);
            e[4 + r] = exp2f(S[mt][blk][1][r]);
          }
          pp[mt][blk] = pack8t(e);
        }

      // O^T += V^T P^T ; psum += ones·P^T
#pragma unroll
      for (int blk = 0; blk < 2; blk++) {
#pragma unroll
        for (int dt = 0; dt < 4; dt++) {
          O[0][dt] = __builtin_amdgcn_mfma_f32_16x16x32_bf16(vf[dt][blk], pp[0][blk], O[0][dt], 0, 0, 0);
          O[1][dt] = __builtin_amdgcn_mfma_f32_16x16x32_bf16(vf[dt][blk], pp[1][blk], O[1][dt], 0, 0, 0);
        }
        psA[0] = __builtin_amdgcn_mfma_f32_16x16x32_bf16(ones, pp[0][blk], psA[0], 0, 0, 0);
        psA[1] = __builtin_amdgcn_mfma_f32_16x16x32_bf16(ones, pp[1][blk], psA[1], 0, 0, 0);
      }

      __syncthreads();
    }
  }

  const int bb = bh >> 4, h = bh & 15;
#pragma unroll
  for (int mt = 0; mt < 2; mt++) {
    float rinv = 1.0f / psA[mt][0];
    const int t = qr + mt * 16 + l15;
#pragma unroll
    for (int dt = 0; dt < 4; dt++) {
      bf16x4 ov = { f2bf(O[mt][dt][0] * rinv), f2bf(O[mt][dt][1] * rinv),
                    f2bf(O[mt][dt][2] * rinv), f2bf(O[mt][dt][3] * rinv) };
      *(bf16x4*)&ctx[(size_t)(bb * SEQ + t) * DM + h * 64 + dt * 16 + quad * 4] = ov;
    }
  }
}

// ---------------- Kernel 3: output projection GEMM (counted vmcnt) ----------------
__global__ __launch_bounds__(256, 2)
void out_gemm(const short* __restrict__ Cx, const short* __restrict__ Ob,
              const float* __restrict__ bias, float* __restrict__ Y) {
  __shared__ short As[2][128 * 64];
  __shared__ short Bs[2][128 * 64];
  const int tid  = threadIdx.x;
  const int m0   = blockIdx.x * 128;
  const int n0   = blockIdx.y * 128;
  const int lane = tid & 63;
  const int w    = tid >> 6;
  const int wm   = (w >> 1) * 64, wn = (w & 1) * 64;
  const int l15  = lane & 15, quad = lane >> 4;

  int g_row[4], g_col[4];
#pragma unroll
  for (int p = 0; p < 4; p++) {
    int r = p * 32 + w * 8 + (lane >> 3);
    g_row[p] = r;
    g_col[p] = ((lane & 7) ^ swz(r)) << 3;
  }
  int aoff[4][2], boff[4][2];
#pragma unroll
  for (int i = 0; i < 4; i++)
#pragma unroll
    for (int ks = 0; ks < 2; ks++) {
      int Ra = wm + i * 16 + l15;
      aoff[i][ks] = Ra * 128 + (((ks * 4 + quad) ^ swz(Ra)) << 4);
      int Rb = wn + i * 16 + l15;
      boff[i][ks] = Rb * 128 + (((ks * 4 + quad) ^ swz(Rb)) << 4);
    }

  f32x4 acc[4][4];
  for (int i = 0; i < 4; i++)
    for (int j = 0; j < 4; j++) acc[i][j] = (f32x4)0.0f;

#pragma unroll
  for (int p = 0; p < 4; p++) {
    gl2lds16(&Cx[(size_t)(m0 + g_row[p]) * DM + g_col[p]], &As[0][(p * 32 + w * 8) * 64]);
    gl2lds16(&Ob[(size_t)(n0 + g_row[p]) * DM + g_col[p]], &Bs[0][(p * 32 + w * 8) * 64]);
  }

  for (int t = 0; t < 16; t++) {
    const int cur = t & 1;
    if (t + 1 < 16) {
      const int kk = (t + 1) * 64;
#pragma unroll
      for (int p = 0; p < 4; p++) {
        gl2lds16(&Cx[(size_t)(m0 + g_row[p]) * DM + kk + g_col[p]], &As[cur ^ 1][(p * 32 + w * 8) * 64]);
        gl2lds16(&Ob[(size_t)(n0 + g_row[p]) * DM + kk + g_col[p]], &Bs[cur ^ 1][(p * 32 + w * 8) * 64]);
      }
      asm volatile("s_waitcnt vmcnt(8)" ::: "memory");
    } else {
      asm volatile("s_waitcnt vmcnt(0)" ::: "memory");
    }
    __builtin_amdgcn_s_barrier();
    __builtin_amdgcn_sched_barrier(0);

    const char* Ab = (const char*)&As[cur][0];
    const char* Bb = (const char*)&Bs[cur][0];
#pragma unroll
    for (int ks = 0; ks < 2; ks++) {
      bf16x8 af[4], bfr[4];
      for (int i = 0; i < 4; i++) af[i]  = *(const bf16x8*)(Ab + aoff[i][ks]);
      for (int j = 0; j < 4; j++) bfr[j] = *(const bf16x8*)(Bb + boff[j][ks]);
      for (int i = 0; i < 4; i++)
        for (int j = 0; j < 4; j++)
          acc[i][j] = __builtin_amdgcn_mfma_f32_16x16x32_bf16(af[i], bfr[j], acc[i][j], 0, 0, 0);
    }
    __builtin_amdgcn_sched_barrier(0);
    __builtin_amdgcn_s_barrier();
    __builtin_amdgcn_sched_barrier(0);
  }

  for (int i = 0; i < 4; i++) {
    const int m = m0 + wm + i * 16 + quad * 4;
    for (int j = 0; j < 4; j++) {
      const int n = n0 + wn + j * 16 + l15;
      const float bv = bias[n];
      for (int r = 0; r < 4; r++)
        Y[(size_t)(m + r) * DM + n] = acc[i][j][r] + bv;
    }
  }
}

extern "C" void kernel_launch(void* const* d_in, const int* in_sizes, int n_in,
                              void* d_out, int out_size, void* d_ws, size_t ws_size,
                              hipStream_t stream) {
  const float* x     = (const float*)d_in[0];
  const float* qkv_w = (const float*)d_in[1];
  const float* qkv_b = (const float*)d_in[2];
  const float* out_w = (const float*)d_in[3];
  const float* out_b = (const float*)d_in[4];
  float* out = (float*)d_out;

  const size_t NBH = (size_t)4 * 16 * SEQ * 64;   // 8,388,608 elements
  short* Q   = (short*)d_ws;
  short* K   = Q + NBH;
  short* Vt  = K + NBH;
  short* ctx = Vt + NBH;     // before attn, holds Xb (bf16 x)
  short* Xb  = ctx;
  short* Wb  = (short*)d_out; // bf16 qkv_w scratch in d_out (dead until out_gemm)

  // Ob placement: if workspace has 2MiB slack past the 64MiB in use, put
  // bf16 out_w there -> its cvt has no dependency on attn, and all three
  // converts merge into ONE front kernel (4 launches total). Otherwise
  // fall back to aliasing Vt (cvt must wait for attn; 5 launches).
  const size_t used  = 4 * NBH * sizeof(short);            // 64 MiB
  const size_t obsz  = (size_t)DM * DM * sizeof(short);    // 2 MiB
  const bool   bigws = ws_size >= used + obsz;

  if (bigws) {
    short* Ob = (short*)((char*)d_ws + used);
    cvt_bf16_3<<<dim3(8192 + 3072 + 1024), 256, 0, stream>>>(
        x, Xb, 8192, qkv_w, Wb, 3072, out_w, Ob);
    qkv_gemm<<<dim3(64, 24), 256, 0, stream>>>(Xb, Wb, qkv_b, Q, K, Vt);
    attn<<<dim3(SEQ / 128, 64), 256, 0, stream>>>(Q, K, Vt, ctx);
    out_gemm<<<dim3(64, 8), 256, 0, stream>>>(ctx, Ob, out_b, out);
  } else {
    short* Ob = Vt;            // alias: only valid after attn is done
    cvt_bf16_2<<<dim3(8192 + 3072), 256, 0, stream>>>(x, Xb, 8192, qkv_w, Wb);
    qkv_gemm<<<dim3(64, 24), 256, 0, stream>>>(Xb, Wb, qkv_b, Q, K, Vt);
    attn<<<dim3(SEQ / 128, 64), 256, 0, stream>>>(Q, K, Vt, ctx);
    cvt_bf16<<<dim3(1024), 256, 0, stream>>>(out_w, Ob);
    out_gemm<<<dim3(64, 8), 256, 0, stream>>>(ctx, Ob, out_b, out);
  }
}

// Round 15
// 251.396 us; speedup vs baseline: 1.1240x; 1.1018x over previous
//
#include <hip/hip_runtime.h>
#include <hip/hip_bf16.h>
#include <cstdint>
#include <cstddef>

// MultiHeadAttention: B=4, T=2048, D=1024, H=16, dh=64, fp32 in/out.
// R13: R12's inline-asm v_exp_f32 produced NaN -- TRANS-pipe result
// latency is NOT interlocked; a bare asm() block hides the hazard from
// the compiler, so the consumer read the dest before the op retired.
// Same theory, correct vehicle: __builtin_amdgcn_exp2f (llvm.amdgcn.exp2)
// emits v_exp_f32 through isel, with wait-states handled. Everything else
// byte-identical to R11 (verified 277.0us: counted-vmcnt 128^2 GEMMs,
// XCD-remapped attn [FETCH 26MB], merged 3-way front cvt, 4 launches).
// (R13 container-failed, R14 acquisition-timed-out -- third submission.)

#define SEQ 2048
#define DM 1024

typedef __attribute__((ext_vector_type(8))) short bf16x8;
typedef __attribute__((ext_vector_type(4))) short bf16x4;
typedef __attribute__((ext_vector_type(4))) float f32x4;

static __device__ __forceinline__ short f2bf(float f) {
  union { float f; uint32_t u; } v; v.f = f;
  uint32_t r = v.u + 0x7fffu + ((v.u >> 16) & 1u);
  return (short)(r >> 16);
}

// native 2^x via compiler intrinsic (single v_exp_f32, hazards handled)
static __device__ __forceinline__ float exp2_native(float x) {
  return __builtin_amdgcn_exp2f(x);
}

typedef const __attribute__((address_space(1))) unsigned int* gas_ptr;
typedef __attribute__((address_space(3))) unsigned int* las_ptr;
static __device__ __forceinline__ void gl2lds16(const void* g, void* l) {
  __builtin_amdgcn_global_load_lds((gas_ptr)g, (las_ptr)l, 16, 0, 0);
}

// truncating pack of two fp32 into bf16 pair: one v_perm_b32
static __device__ __forceinline__ unsigned permhi(float a_odd, float a_even) {
  union { float f; unsigned u; } x, y; x.f = a_odd; y.f = a_even;
  return __builtin_amdgcn_perm(x.u, y.u, 0x07060302u);
}
static __device__ __forceinline__ bf16x8 pack8t(const float* e) {
  union { bf16x8 v; unsigned u[4]; } r;
  r.u[0] = permhi(e[1], e[0]);
  r.u[1] = permhi(e[3], e[2]);
  r.u[2] = permhi(e[5], e[4]);
  r.u[3] = permhi(e[7], e[6]);
  return r.v;
}

// swizzle: chunk c (16B) of tile row r stored at LDS chunk r*8 + (c ^ swz(r))
static __device__ __forceinline__ int swz(int r) {
  return (r & 3) | (((r >> 3) & 1) << 2);
}

// ---------------- Kernel 0: fp32 -> bf16 convert ----------------
__global__ __launch_bounds__(256)
void cvt_bf16(const float* __restrict__ src, short* __restrict__ dst) {
  int i = blockIdx.x * 256 + threadIdx.x;
  float4 v = ((const float4*)src)[i];
  bf16x4 p = { f2bf(v.x), f2bf(v.y), f2bf(v.z), f2bf(v.w) };
  ((bf16x4*)dst)[i] = p;
}

// merged convert, two segments
__global__ __launch_bounds__(256)
void cvt_bf16_2(const float* __restrict__ src1, short* __restrict__ dst1, int n1,
                const float* __restrict__ src2, short* __restrict__ dst2) {
  int b = blockIdx.x;
  const float* s; short* d; int i;
  if (b < n1) { s = src1; d = dst1; i = b * 256 + threadIdx.x; }
  else        { s = src2; d = dst2; i = (b - n1) * 256 + threadIdx.x; }
  float4 v = ((const float4*)s)[i];
  bf16x4 p = { f2bf(v.x), f2bf(v.y), f2bf(v.z), f2bf(v.w) };
  ((bf16x4*)d)[i] = p;
}

// merged convert, three segments
__global__ __launch_bounds__(256)
void cvt_bf16_3(const float* __restrict__ src1, short* __restrict__ dst1, int n1,
                const float* __restrict__ src2, short* __restrict__ dst2, int n2,
                const float* __restrict__ src3, short* __restrict__ dst3) {
  int b = blockIdx.x;
  const float* s; short* d; int i;
  if (b < n1)           { s = src1; d = dst1; i = b * 256 + threadIdx.x; }
  else if (b < n1 + n2) { s = src2; d = dst2; i = (b - n1) * 256 + threadIdx.x; }
  else                  { s = src3; d = dst3; i = (b - n1 - n2) * 256 + threadIdx.x; }
  float4 v = ((const float4*)s)[i];
  bf16x4 p = { f2bf(v.x), f2bf(v.y), f2bf(v.z), f2bf(v.w) };
  ((bf16x4*)d)[i] = p;
}

// ---------------- Kernel 1: QKV projection GEMM (prefetch + counted vmcnt) ----------------
__global__ __launch_bounds__(256, 2)
void qkv_gemm(const short* __restrict__ Xb, const short* __restrict__ Wb,
              const float* __restrict__ bias,
              short* __restrict__ Q, short* __restrict__ K,
              short* __restrict__ Vt) {
  __shared__ short As[2][128 * 64];
  __shared__ short Bs[2][128 * 64];
  const int tid  = threadIdx.x;
  const int m0   = blockIdx.x * 128;
  const int n0   = blockIdx.y * 128;
  const int lane = tid & 63;
  const int w    = tid >> 6;
  const int wm   = (w >> 1) * 64, wn = (w & 1) * 64;
  const int l15  = lane & 15, quad = lane >> 4;

  // staging map (swizzled source, linear LDS dest)
  int g_row[4], g_col[4];
#pragma unroll
  for (int p = 0; p < 4; p++) {
    int r = p * 32 + w * 8 + (lane >> 3);
    g_row[p] = r;
    g_col[p] = ((lane & 7) ^ swz(r)) << 3;
  }
  // cached swizzled read byte-offsets
  int aoff[4][2], boff[4][2];
#pragma unroll
  for (int i = 0; i < 4; i++)
#pragma unroll
    for (int ks = 0; ks < 2; ks++) {
      int Ra = wm + i * 16 + l15;
      aoff[i][ks] = Ra * 128 + (((ks * 4 + quad) ^ swz(Ra)) << 4);
      int Rb = wn + i * 16 + l15;
      boff[i][ks] = Rb * 128 + (((ks * 4 + quad) ^ swz(Rb)) << 4);
    }

  f32x4 acc[4][4];
  for (int i = 0; i < 4; i++)
    for (int j = 0; j < 4; j++) acc[i][j] = (f32x4)0.0f;

  // prologue: stage K-tile 0 into buffer 0
#pragma unroll
  for (int p = 0; p < 4; p++) {
    gl2lds16(&Xb[(size_t)(m0 + g_row[p]) * DM + g_col[p]], &As[0][(p * 32 + w * 8) * 64]);
    gl2lds16(&Wb[(size_t)(n0 + g_row[p]) * DM + g_col[p]], &Bs[0][(p * 32 + w * 8) * 64]);
  }

  for (int t = 0; t < 16; t++) {
    const int cur = t & 1;
    if (t + 1 < 16) {
      const int kk = (t + 1) * 64;
#pragma unroll
      for (int p = 0; p < 4; p++) {
        gl2lds16(&Xb[(size_t)(m0 + g_row[p]) * DM + kk + g_col[p]], &As[cur ^ 1][(p * 32 + w * 8) * 64]);
        gl2lds16(&Wb[(size_t)(n0 + g_row[p]) * DM + kk + g_col[p]], &Bs[cur ^ 1][(p * 32 + w * 8) * 64]);
      }
      asm volatile("s_waitcnt vmcnt(8)" ::: "memory");   // tile t landed; t+1 in flight
    } else {
      asm volatile("s_waitcnt vmcnt(0)" ::: "memory");
    }
    __builtin_amdgcn_s_barrier();
    __builtin_amdgcn_sched_barrier(0);

    const char* Ab = (const char*)&As[cur][0];
    const char* Bb = (const char*)&Bs[cur][0];
#pragma unroll
    for (int ks = 0; ks < 2; ks++) {
      bf16x8 af[4], bfr[4];
      for (int i = 0; i < 4; i++) af[i]  = *(const bf16x8*)(Ab + aoff[i][ks]);
      for (int j = 0; j < 4; j++) bfr[j] = *(const bf16x8*)(Bb + boff[j][ks]);
      for (int i = 0; i < 4; i++)
        for (int j = 0; j < 4; j++)
          acc[i][j] = __builtin_amdgcn_mfma_f32_16x16x32_bf16(af[i], bfr[j], acc[i][j], 0, 0, 0);
    }
    __builtin_amdgcn_sched_barrier(0);
    __builtin_amdgcn_s_barrier();     // readers of buf done before next stage overwrites
    __builtin_amdgcn_sched_barrier(0);
  }

  const float C1 = 0.18033688011112042f;   // 0.125 * log2(e), folded into Q
  const int qkv = n0 >> 10;
  for (int i = 0; i < 4; i++) {
    const int m = m0 + wm + i * 16 + quad * 4;
    const int bb = m >> 11, t = m & 2047;
    for (int j = 0; j < 4; j++) {
      const int f  = n0 + wn + j * 16 + l15;
      const int fi = f & 1023;
      const int h  = fi >> 6, d = fi & 63;
      const float bv = bias[f];
      if (qkv == 2) {
        bf16x4 pk = { f2bf(acc[i][j][0] + bv), f2bf(acc[i][j][1] + bv),
                      f2bf(acc[i][j][2] + bv), f2bf(acc[i][j][3] + bv) };
        *(bf16x4*)&Vt[((size_t)(bb * 16 + h) * 64 + d) * SEQ + t] = pk;
      } else {
        short* dst = (qkv == 0) ? Q : K;
        const float sc = (qkv == 0) ? C1 : 1.0f;
        size_t base = ((size_t)(bb * 16 + h) * SEQ + t) * 64 + d;
        for (int r = 0; r < 4; r++)
          dst[base + (size_t)r * 64] = f2bf((acc[i][j][r] + bv) * sc);
      }
    }
  }
}

// ---------------- Kernel 2: flash attention (LDS-staged K/V) ----------------
// Schedule/layout byte-identical to R9/R11 (verified ~108us; XCD remap
// keeps per-XCD K/V L2-resident: FETCH 26MB). R13: exp2f -> builtin exp2.
__global__ __launch_bounds__(256, 4)
void attn(const short* __restrict__ Q, const short* __restrict__ K,
          const short* __restrict__ Vt, short* __restrict__ ctx) {
  __shared__ short Ks[2][64 * 64];   // 8 KB per buffer, swizzled chunks
  __shared__ short Vs[2][64 * 64];
  const int tid  = threadIdx.x;
  const int w    = tid >> 6, lane = tid & 63;
  const int l15  = lane & 15, quad = lane >> 4;

  // XCD-aware remap (T1): linear id L, xcd = L&7 (HW round-robin),
  // bh = ((L>>3)>>4)*8 + xcd, bx = (L>>3)&15. Bijective on [0,1024).
  const int L    = blockIdx.y * 16 + blockIdx.x;
  const int m_   = L >> 3;
  const int bh   = ((m_ >> 4) << 3) | (L & 7);
  const int qr   = (m_ & 15) * 128 + w * 32;

  const short* Kb = &K[(size_t)bh * SEQ * 64];
  const short* Vb = &Vt[(size_t)bh * 64 * SEQ];

  const int kperm = (l15 >> 2) * 8 + (l15 & 3);   // + tau*4 -> permuted K row

  int dr[2], dc[2];
#pragma unroll
  for (int p = 0; p < 2; p++) {
    int ci = p * 256 + w * 64 + lane;
    dr[p] = ci >> 3;
    dc[p] = (ci & 7) ^ swz(ci >> 3);
  }
  const short* kp[2];
  const short* vp[2];
#pragma unroll
  for (int p = 0; p < 2; p++) {
    kp[p] = &Kb[(size_t)(64 + dr[p]) * 64 + dc[p] * 8];
    vp[p] = &Vb[(size_t)dr[p] * SEQ + 64 + dc[p] * 8];
  }

  int koff[2][2][2][2];   // [buf][blk][tau][ks]
  int voff[2][4][2];      // [buf][dt][blk]
#pragma unroll
  for (int blk = 0; blk < 2; blk++)
#pragma unroll
    for (int tau = 0; tau < 2; tau++)
#pragma unroll
      for (int ks = 0; ks < 2; ks++) {
        int R = blk * 32 + kperm + tau * 4;
        int c = (ks * 4 + quad) ^ swz(R);
        int off = (R * 8 + c) * 16;
        koff[0][blk][tau][ks] = off;
        koff[1][blk][tau][ks] = off + 8192;
      }
#pragma unroll
  for (int dt = 0; dt < 4; dt++)
#pragma unroll
    for (int blk = 0; blk < 2; blk++) {
      int R = dt * 16 + l15;
      int c = (blk * 4 + quad) ^ swz(R);
      int off = (R * 8 + c) * 16;
      voff[0][dt][blk] = off;
      voff[1][dt][blk] = off + 8192;
    }
  const char* KsB = (const char*)&Ks[0][0];
  const char* VsB = (const char*)&Vs[0][0];

  bf16x8 qf[2][2];
#pragma unroll
  for (int mt = 0; mt < 2; mt++)
#pragma unroll
    for (int ks = 0; ks < 2; ks++)
      qf[mt][ks] = *(const bf16x8*)&Q[(size_t)bh * SEQ * 64 + (size_t)(qr + mt * 16 + l15) * 64 + ks * 32 + quad * 8];

  f32x4 O[2][4];
#pragma unroll
  for (int mt = 0; mt < 2; mt++)
    for (int dt = 0; dt < 4; dt++) O[mt][dt] = (f32x4)0.0f;
  f32x4 psA[2];
  psA[0] = (f32x4)0.0f; psA[1] = (f32x4)0.0f;
  const short one_bf = (short)0x3F80;
  const bf16x8 ones = { one_bf, one_bf, one_bf, one_bf, one_bf, one_bf, one_bf, one_bf };

  // prologue: DMA tile 0 into buffer 0
#pragma unroll
  for (int p = 0; p < 2; p++) {
    gl2lds16(&Kb[(size_t)dr[p] * 64 + dc[p] * 8],  &Ks[0][(p * 256 + w * 64) * 8]);
    gl2lds16(&Vb[(size_t)dr[p] * SEQ + dc[p] * 8], &Vs[0][(p * 256 + w * 64) * 8]);
  }
  __syncthreads();

  for (int k0 = 0; k0 < SEQ; k0 += 128) {
#pragma unroll
    for (int half = 0; half < 2; half++) {
      // prefetch next tile into the other buffer
      const bool doPf = (half == 0) || (k0 + 128 < SEQ);
      if (doPf) {
#pragma unroll
        for (int p = 0; p < 2; p++) {
          gl2lds16(kp[p], &Ks[half ^ 1][(p * 256 + w * 64) * 8]);
          gl2lds16(vp[p], &Vs[half ^ 1][(p * 256 + w * 64) * 8]);
        }
      }
#pragma unroll
      for (int p = 0; p < 2; p++) { kp[p] += 64 * 64; vp[p] += 64; }

      // K fragments (cached offsets)
      bf16x8 kf[2][2][2];
#pragma unroll
      for (int blk = 0; blk < 2; blk++)
#pragma unroll
        for (int tau = 0; tau < 2; tau++)
#pragma unroll
          for (int ks = 0; ks < 2; ks++)
            kf[blk][tau][ks] = *(const bf16x8*)(KsB + koff[half][blk][tau][ks]);

      // S^T = K Q^T
      f32x4 S[2][2][2];
#pragma unroll
      for (int mt = 0; mt < 2; mt++)
#pragma unroll
        for (int blk = 0; blk < 2; blk++) {
          f32x4 S0 = (f32x4)0.0f, S1 = (f32x4)0.0f;
#pragma unroll
          for (int ks = 0; ks < 2; ks++) {
            S0 = __builtin_amdgcn_mfma_f32_16x16x32_bf16(kf[blk][0][ks], qf[mt][ks], S0, 0, 0, 0);
            S1 = __builtin_amdgcn_mfma_f32_16x16x32_bf16(kf[blk][1][ks], qf[mt][ks], S1, 0, 0, 0);
          }
          S[mt][blk][0] = S0; S[mt][blk][1] = S1;
        }

      // V^T fragments (cached offsets)
      bf16x8 vf[4][2];
#pragma unroll
      for (int dt = 0; dt < 4; dt++)
#pragma unroll
        for (int blk = 0; blk < 2; blk++)
          vf[dt][blk] = *(const bf16x8*)(VsB + voff[half][dt][blk]);

      // p = 2^S (builtin v_exp_f32) ; truncating v_perm pack into PV B-frags
      bf16x8 pp[2][2];
#pragma unroll
      for (int mt = 0; mt < 2; mt++)
#pragma unroll
        for (int blk = 0; blk < 2; blk++) {
          float e[8];
#pragma unroll
          for (int r = 0; r < 4; r++) {
            e[r]     = exp2_native(S[mt][blk][0][r]);
            e[4 + r] = exp2_native(S[mt][blk][1][r]);
          }
          pp[mt][blk] = pack8t(e);
        }

      // O^T += V^T P^T ; psum += ones·P^T
#pragma unroll
      for (int blk = 0; blk < 2; blk++) {
#pragma unroll
        for (int dt = 0; dt < 4; dt++) {
          O[0][dt] = __builtin_amdgcn_mfma_f32_16x16x32_bf16(vf[dt][blk], pp[0][blk], O[0][dt], 0, 0, 0);
          O[1][dt] = __builtin_amdgcn_mfma_f32_16x16x32_bf16(vf[dt][blk], pp[1][blk], O[1][dt], 0, 0, 0);
        }
        psA[0] = __builtin_amdgcn_mfma_f32_16x16x32_bf16(ones, pp[0][blk], psA[0], 0, 0, 0);
        psA[1] = __builtin_amdgcn_mfma_f32_16x16x32_bf16(ones, pp[1][blk], psA[1], 0, 0, 0);
      }

      __syncthreads();
    }
  }

  const int bb = bh >> 4, h = bh & 15;
#pragma unroll
  for (int mt = 0; mt < 2; mt++) {
    float rinv = 1.0f / psA[mt][0];
    const int t = qr + mt * 16 + l15;
#pragma unroll
    for (int dt = 0; dt < 4; dt++) {
      bf16x4 ov = { f2bf(O[mt][dt][0] * rinv), f2bf(O[mt][dt][1] * rinv),
                    f2bf(O[mt][dt][2] * rinv), f2bf(O[mt][dt][3] * rinv) };
      *(bf16x4*)&ctx[(size_t)(bb * SEQ + t) * DM + h * 64 + dt * 16 + quad * 4] = ov;
    }
  }
}

// ---------------- Kernel 3: output projection GEMM (counted vmcnt) ----------------
__global__ __launch_bounds__(256, 2)
void out_gemm(const short* __restrict__ Cx, const short* __restrict__ Ob,
              const float* __restrict__ bias, float* __restrict__ Y) {
  __shared__ short As[2][128 * 64];
  __shared__ short Bs[2][128 * 64];
  const int tid  = threadIdx.x;
  const int m0   = blockIdx.x * 128;
  const int n0   = blockIdx.y * 128;
  const int lane = tid & 63;
  const int w    = tid >> 6;
  const int wm   = (w >> 1) * 64, wn = (w & 1) * 64;
  const int l15  = lane & 15, quad = lane >> 4;

  int g_row[4], g_col[4];
#pragma unroll
  for (int p = 0; p < 4; p++) {
    int r = p * 32 + w * 8 + (lane >> 3);
    g_row[p] = r;
    g_col[p] = ((lane & 7) ^ swz(r)) << 3;
  }
  int aoff[4][2], boff[4][2];
#pragma unroll
  for (int i = 0; i < 4; i++)
#pragma unroll
    for (int ks = 0; ks < 2; ks++) {
      int Ra = wm + i * 16 + l15;
      aoff[i][ks] = Ra * 128 + (((ks * 4 + quad) ^ swz(Ra)) << 4);
      int Rb = wn + i * 16 + l15;
      boff[i][ks] = Rb * 128 + (((ks * 4 + quad) ^ swz(Rb)) << 4);
    }

  f32x4 acc[4][4];
  for (int i = 0; i < 4; i++)
    for (int j = 0; j < 4; j++) acc[i][j] = (f32x4)0.0f;

#pragma unroll
  for (int p = 0; p < 4; p++) {
    gl2lds16(&Cx[(size_t)(m0 + g_row[p]) * DM + g_col[p]], &As[0][(p * 32 + w * 8) * 64]);
    gl2lds16(&Ob[(size_t)(n0 + g_row[p]) * DM + g_col[p]], &Bs[0][(p * 32 + w * 8) * 64]);
  }

  for (int t = 0; t < 16; t++) {
    const int cur = t & 1;
    if (t + 1 < 16) {
      const int kk = (t + 1) * 64;
#pragma unroll
      for (int p = 0; p < 4; p++) {
        gl2lds16(&Cx[(size_t)(m0 + g_row[p]) * DM + kk + g_col[p]], &As[cur ^ 1][(p * 32 + w * 8) * 64]);
        gl2lds16(&Ob[(size_t)(n0 + g_row[p]) * DM + kk + g_col[p]], &Bs[cur ^ 1][(p * 32 + w * 8) * 64]);
      }
      asm volatile("s_waitcnt vmcnt(8)" ::: "memory");
    } else {
      asm volatile("s_waitcnt vmcnt(0)" ::: "memory");
    }
    __builtin_amdgcn_s_barrier();
    __builtin_amdgcn_sched_barrier(0);

    const char* Ab = (const char*)&As[cur][0];
    const char* Bb = (const char*)&Bs[cur][0];
#pragma unroll
    for (int ks = 0; ks < 2; ks++) {
      bf16x8 af[4], bfr[4];
      for (int i = 0; i < 4; i++) af[i]  = *(const bf16x8*)(Ab + aoff[i][ks]);
      for (int j = 0; j < 4; j++) bfr[j] = *(const bf16x8*)(Bb + boff[j][ks]);
      for (int i = 0; i < 4; i++)
        for (int j = 0; j < 4; j++)
          acc[i][j] = __builtin_amdgcn_mfma_f32_16x16x32_bf16(af[i], bfr[j], acc[i][j], 0, 0, 0);
    }
    __builtin_amdgcn_sched_barrier(0);
    __builtin_amdgcn_s_barrier();
    __builtin_amdgcn_sched_barrier(0);
  }

  for (int i = 0; i < 4; i++) {
    const int m = m0 + wm + i * 16 + quad * 4;
    for (int j = 0; j < 4; j++) {
      const int n = n0 + wn + j * 16 + l15;
      const float bv = bias[n];
      for (int r = 0; r < 4; r++)
        Y[(size_t)(m + r) * DM + n] = acc[i][j][r] + bv;
    }
  }
}

extern "C" void kernel_launch(void* const* d_in, const int* in_sizes, int n_in,
                              void* d_out, int out_size, void* d_ws, size_t ws_size,
                              hipStream_t stream) {
  const float* x     = (const float*)d_in[0];
  const float* qkv_w = (const float*)d_in[1];
  const float* qkv_b = (const float*)d_in[2];
  const float* out_w = (const float*)d_in[3];
  const float* out_b = (const float*)d_in[4];
  float* out = (float*)d_out;

  const size_t NBH = (size_t)4 * 16 * SEQ * 64;   // 8,388,608 elements
  short* Q   = (short*)d_ws;
  short* K   = Q + NBH;
  short* Vt  = K + NBH;
  short* ctx = Vt + NBH;     // before attn, holds Xb (bf16 x)
  short* Xb  = ctx;
  short* Wb  = (short*)d_out; // bf16 qkv_w scratch in d_out (dead until out_gemm)

  // Ob placement: if workspace has 2MiB slack past the 64MiB in use, put
  // bf16 out_w there -> its cvt has no dependency on attn, and all three
  // converts merge into ONE front kernel (4 launches total). Otherwise
  // fall back to aliasing Vt (cvt must wait for attn; 5 launches).
  const size_t used  = 4 * NBH * sizeof(short);            // 64 MiB
  const size_t obsz  = (size_t)DM * DM * sizeof(short);    // 2 MiB
  const bool   bigws = ws_size >= used + obsz;

  if (bigws) {
    short* Ob = (short*)((char*)d_ws + used);
    cvt_bf16_3<<<dim3(8192 + 3072 + 1024), 256, 0, stream>>>(
        x, Xb, 8192, qkv_w, Wb, 3072, out_w, Ob);
    qkv_gemm<<<dim3(64, 24), 256, 0, stream>>>(Xb, Wb, qkv_b, Q, K, Vt);
    attn<<<dim3(SEQ / 128, 64), 256, 0, stream>>>(Q, K, Vt, ctx);
    out_gemm<<<dim3(64, 8), 256, 0, stream>>>(ctx, Ob, out_b, out);
  } else {
    short* Ob = Vt;            // alias: only valid after attn is done
    cvt_bf16_2<<<dim3(8192 + 3072), 256, 0, stream>>>(x, Xb, 8192, qkv_w, Wb);
    qkv_gemm<<<dim3(64, 24), 256, 0, stream>>>(Xb, Wb, qkv_b, Q, K, Vt);
    attn<<<dim3(SEQ / 128, 64), 256, 0, stream>>>(Q, K, Vt, ctx);
    cvt_bf16<<<dim3(1024), 256, 0, stream>>>(out_w, Ob);
    out_gemm<<<dim3(64, 8), 256, 0, stream>>>(ctx, Ob, out_b, out);
  }
}